// Round 3
// baseline (2684.616 us; speedup 1.0000x reference)
//
#include <hip/hip_runtime.h>

typedef unsigned short u16;
typedef unsigned int u32;
typedef __attribute__((ext_vector_type(8))) short short8;
typedef __attribute__((ext_vector_type(4))) float fx4;

#define BATCH 4096
#define TSEQ 12
#define DIN 1536
#define DS 234
#define KTOT 1770
#define KPAD 1792
#define COUT 234
#define MROWS (BATCH * TSEQ)   // 49152

union F4 { float4 v; float f[4]; u32 u[4]; };
union ABFrag { u32 u[4]; short8 s; uint4 q4; };

// persistent intermediates (module-static: no hipMalloc inside kernel_launch)
__device__ __attribute__((aligned(256))) u16 gWhi[64 * KPAD];
__device__ __attribute__((aligned(256))) u16 gWlo[64 * KPAD];
__device__ __attribute__((aligned(256))) float gH[(size_t)MROWS * 64];

// split x = hi + lo, hi = truncate-to-bf16 (top 16 bits), lo = bf16(x - hi).
// 3-term MFMA (ah*bh + al*bh + ah*bl) -> ~2^-15 relative product error.
__device__ __forceinline__ void splitPair(float x0, float x1, u32& hi, u32& lo) {
    union { float f; u32 u; } c0, c1, l0, l1;
    union { u32 u; float f; } g0, g1;
    c0.f = x0; c1.f = x1;
    u32 h0 = c0.u & 0xFFFF0000u;
    u32 h1 = c1.u & 0xFFFF0000u;
    g0.u = h0; g1.u = h1;
    l0.f = x0 - g0.f;
    l1.f = x1 - g1.f;
    hi = (h0 >> 16) | h1;
    lo = (l0.u >> 16) | (l1.u & 0xFFFF0000u);
}

__device__ __forceinline__ void splitFrag(const float a[8], ABFrag& ah, ABFrag& al) {
#pragma unroll
    for (int i = 0; i < 4; i++) splitPair(a[2 * i], a[2 * i + 1], ah.u[i], al.u[i]);
}

// 64-float weight row cached in 16 float4 VGPRs
__device__ __forceinline__ void loadRow(F4 (&w)[16], const float* base) {
#pragma unroll
    for (int i = 0; i < 16; i++) w[i].v = *(const float4*)(base + 4 * i);
}
__device__ __forceinline__ float dot64(const F4 (&w)[16], const float* v) {
    float a = 0.f, b = 0.f;
#pragma unroll
    for (int i = 0; i < 16; i++) {
        F4 h; h.v = *(const float4*)(v + 4 * i);   // LDS broadcast ds_read_b128
        a += w[i].f[0] * h.f[0] + w[i].f[1] * h.f[1];
        b += w[i].f[2] * h.f[2] + w[i].f[3] * h.f[3];
    }
    return a + b;
}

// ---------------- kernel 0: W_in -> bf16 hi/lo planes (K zero-padded to 1792) -------------
__global__ __launch_bounds__(256) void k_wsplit(const float* __restrict__ W_in) {
    int idx = blockIdx.x * 256 + threadIdx.x;        // 0 .. 64*1792-1
    int n = idx / KPAD, k = idx - n * KPAD;
    float w = (k < KTOT) ? W_in[n * KTOT + k] : 0.f;
    union { float f; u32 u; } c; c.f = w;
    u32 h = c.u & 0xFFFF0000u;
    union { u32 u; float f; } g; g.u = h;
    union { float f; u32 u; } l; l.f = w - g.f;
    gWhi[idx] = (u16)(h >> 16);
    gWlo[idx] = (u16)(l.u >> 16);
}

// ---------------- kernel 1: H = gelu(LN(X @ W^T + b)) ; X = [emb | fpass] ------------------
// one wave per block; each wave computes 32 M-rows x 64 cols, K = 1770.
// launch_bounds(64,3): VGPR cap ~168 (need ~110) -> no spills; occupancy is grid-limited.
__global__ __launch_bounds__(64, 3) void k_gemm(
    const float* __restrict__ emb, const float* __restrict__ fpass,
    const float* __restrict__ b_in, const float* __restrict__ ln_in_g,
    const float* __restrict__ ln_in_b)
{
    const int lane = threadIdx.x;
    const int q = lane >> 4, cc = lane & 15;
    const int ko = q * 8;
    const int rowblk = blockIdx.x * 32;

    fx4 acc[2][4];
#pragma unroll
    for (int tl = 0; tl < 2; tl++)
#pragma unroll
        for (int nt = 0; nt < 4; nt++) acc[tl][nt] = (fx4){0.f, 0.f, 0.f, 0.f};

    const float* arows[2];
    const float* frows[2];
#pragma unroll
    for (int tl = 0; tl < 2; tl++) {
        size_t m = (size_t)(rowblk + tl * 16 + cc);
        arows[tl] = emb + m * DIN + ko;
        frows[tl] = fpass + m * DS + ko;
    }
    const u16* whb = gWhi + cc * KPAD + ko;
    const u16* wlb = gWlo + cc * KPAD + ko;

    // emb part: K = 0..1535
    for (int kg = 0; kg < DIN; kg += 32) {
        ABFrag bh[4], bl[4];
#pragma unroll
        for (int nt = 0; nt < 4; nt++) {
            bh[nt].q4 = *(const uint4*)(whb + nt * 16 * KPAD + kg);
            bl[nt].q4 = *(const uint4*)(wlb + nt * 16 * KPAD + kg);
        }
#pragma unroll
        for (int tl = 0; tl < 2; tl++) {
            F4 a0, a1;
            a0.v = *(const float4*)(arows[tl] + kg);
            a1.v = *(const float4*)(arows[tl] + kg + 4);
            float av[8] = {a0.f[0], a0.f[1], a0.f[2], a0.f[3], a1.f[0], a1.f[1], a1.f[2], a1.f[3]};
            ABFrag ah, al;
            splitFrag(av, ah, al);
#pragma unroll
            for (int nt = 0; nt < 4; nt++) {
                acc[tl][nt] = __builtin_amdgcn_mfma_f32_16x16x32_bf16(ah.s, bh[nt].s, acc[tl][nt], 0, 0, 0);
                acc[tl][nt] = __builtin_amdgcn_mfma_f32_16x16x32_bf16(al.s, bh[nt].s, acc[tl][nt], 0, 0, 0);
                acc[tl][nt] = __builtin_amdgcn_mfma_f32_16x16x32_bf16(ah.s, bl[nt].s, acc[tl][nt], 0, 0, 0);
            }
        }
    }
    // fpass part, full 32-wide steps: K = 1536..1759 (elem idx <= 223 < 234)
    for (int kg = 0; kg < 224; kg += 32) {
        ABFrag bh[4], bl[4];
#pragma unroll
        for (int nt = 0; nt < 4; nt++) {
            bh[nt].q4 = *(const uint4*)(whb + nt * 16 * KPAD + DIN + kg);
            bl[nt].q4 = *(const uint4*)(wlb + nt * 16 * KPAD + DIN + kg);
        }
#pragma unroll
        for (int tl = 0; tl < 2; tl++) {
            float2 a0 = *(const float2*)(frows[tl] + kg);
            float2 a1 = *(const float2*)(frows[tl] + kg + 2);
            float2 a2 = *(const float2*)(frows[tl] + kg + 4);
            float2 a3 = *(const float2*)(frows[tl] + kg + 6);
            float av[8] = {a0.x, a0.y, a1.x, a1.y, a2.x, a2.y, a3.x, a3.y};
            ABFrag ah, al;
            splitFrag(av, ah, al);
#pragma unroll
            for (int nt = 0; nt < 4; nt++) {
                acc[tl][nt] = __builtin_amdgcn_mfma_f32_16x16x32_bf16(ah.s, bh[nt].s, acc[tl][nt], 0, 0, 0);
                acc[tl][nt] = __builtin_amdgcn_mfma_f32_16x16x32_bf16(al.s, bh[nt].s, acc[tl][nt], 0, 0, 0);
                acc[tl][nt] = __builtin_amdgcn_mfma_f32_16x16x32_bf16(ah.s, bl[nt].s, acc[tl][nt], 0, 0, 0);
            }
        }
    }
    // tail: elems 224..233 of fpass (W planes are zero-padded past 1770)
    {
        ABFrag bh[4], bl[4];
#pragma unroll
        for (int nt = 0; nt < 4; nt++) {
            bh[nt].q4 = *(const uint4*)(whb + nt * 16 * KPAD + DIN + 224);
            bl[nt].q4 = *(const uint4*)(wlb + nt * 16 * KPAD + DIN + 224);
        }
#pragma unroll
        for (int tl = 0; tl < 2; tl++) {
            float av[8];
#pragma unroll
            for (int j = 0; j < 8; j++) {
                int kk = 224 + ko + j;
                av[j] = (kk < DS) ? frows[tl][224 + j] : 0.f;
            }
            ABFrag ah, al;
            splitFrag(av, ah, al);
#pragma unroll
            for (int nt = 0; nt < 4; nt++) {
                acc[tl][nt] = __builtin_amdgcn_mfma_f32_16x16x32_bf16(ah.s, bh[nt].s, acc[tl][nt], 0, 0, 0);
                acc[tl][nt] = __builtin_amdgcn_mfma_f32_16x16x32_bf16(al.s, bh[nt].s, acc[tl][nt], 0, 0, 0);
                acc[tl][nt] = __builtin_amdgcn_mfma_f32_16x16x32_bf16(ah.s, bl[nt].s, acc[tl][nt], 0, 0, 0);
            }
        }
    }
    // epilogue: bias + LN(64) + GELU -> gH.  C/D: col = nt*16+cc, row = q*4+reg.
    float bia[4], gg[4], bb2[4];
#pragma unroll
    for (int nt = 0; nt < 4; nt++) {
        int col = nt * 16 + cc;
        bia[nt] = b_in[col]; gg[nt] = ln_in_g[col]; bb2[nt] = ln_in_b[col];
    }
#pragma unroll
    for (int tl = 0; tl < 2; tl++) {
#pragma unroll
        for (int rr = 0; rr < 4; rr++) {
            float vv[4], s1 = 0.f, s2 = 0.f;
#pragma unroll
            for (int nt = 0; nt < 4; nt++) {
                vv[nt] = acc[tl][nt][rr] + bia[nt];
                s1 += vv[nt]; s2 += vv[nt] * vv[nt];
            }
#pragma unroll
            for (int off = 1; off <= 8; off <<= 1) {
                s1 += __shfl_xor(s1, off);
                s2 += __shfl_xor(s2, off);
            }
            float mean = s1 * 0.015625f;
            float var = s2 * 0.015625f - mean * mean;
            float rstd = rsqrtf(var + 1e-5f);
            size_t m = (size_t)(rowblk + tl * 16 + q * 4 + rr);
#pragma unroll
            for (int nt = 0; nt < 4; nt++) {
                float x = (vv[nt] - mean) * rstd * gg[nt] + bb2[nt];
                float gel = 0.5f * x * (1.f + erff(x * 0.70710678118654752f));
                gH[m * 64 + nt * 16 + cc] = gel;
            }
        }
    }
}

// ---------------- kernel 2: meta + pos + bidirectional SSM + merge + LN + out --------------
// 128 threads = 2 waves; wave w processes direction w (fwd/bwd are independent until merge).
// All __syncthreads() are reached uniformly by both waves.
__global__ __launch_bounds__(128, 3) void k_ssm(
    const float* __restrict__ site_tab, const float* __restrict__ hour_tab,
    const float* __restrict__ W_meta, const float* __restrict__ b_meta,
    const float* __restrict__ pos_enc,
    const float* __restrict__ Wm, const float* __restrict__ bm,
    const float* __restrict__ lng, const float* __restrict__ lnb,
    const float* __restrict__ Wo, const float* __restrict__ bo,
    const int* __restrict__ site_ids, const int* __restrict__ hours,
    const float* __restrict__ fWxz, const float* __restrict__ fconvw, const float* __restrict__ fconvb,
    const float* __restrict__ fWdt, const float* __restrict__ fbdt, const float* __restrict__ fAlog,
    const float* __restrict__ fDp, const float* __restrict__ fWB, const float* __restrict__ fWC,
    const float* __restrict__ bWxz, const float* __restrict__ bconvw, const float* __restrict__ bconvb,
    const float* __restrict__ bWdt, const float* __restrict__ bbdt, const float* __restrict__ bAlog,
    const float* __restrict__ bDp, const float* __restrict__ bWB, const float* __restrict__ bWC,
    float* __restrict__ out)
{
    __shared__ __attribute__((aligned(16))) float Hs[TSEQ * 64];
    __shared__ __attribute__((aligned(16))) float Xs[2][TSEQ * 68];
    __shared__ __attribute__((aligned(16))) float BCs[2][TSEQ * 16];
    __shared__ __attribute__((aligned(16))) float Ys[TSEQ * 128];
    __shared__ __attribute__((aligned(16))) float Ms[TSEQ * 64];

    const int lane = threadIdx.x & 63;
    const int w = threadIdx.x >> 6;          // wave id == direction
    const int b = blockIdx.x;

    // meta for this lane's channel (computed redundantly by both waves)
    float metaV;
    {
        int sid = min(max(site_ids[b], 0), 19);
        int hr  = min(max(hours[b], 0), 23);
        float a = b_meta[lane];
#pragma unroll
        for (int j = 0; j < 8; j++) a += site_tab[sid * 8 + j] * W_meta[lane * 16 + j];
#pragma unroll
        for (int j = 0; j < 8; j++) a += hour_tab[hr * 8 + j] * W_meta[lane * 16 + 8 + j];
        metaV = a;
    }
    // H load + pos + meta: wave w writes t = 6w .. 6w+5
#pragma unroll
    for (int tt = 0; tt < 6; tt++) {
        int t = w * 6 + tt;
        Hs[t * 64 + lane] = gH[((size_t)b * TSEQ + t) * 64 + lane] + pos_enc[t * 64 + lane] + metaV;
    }
    __syncthreads();

    // ---- per-direction SSM (wave w handles dir w; lane = channel d)
    {
        const int dir = w;
        const float* Wxz  = dir ? bWxz  : fWxz;
        const float* cw   = dir ? bconvw : fconvw;
        const float* cbp  = dir ? bconvb : fconvb;
        const float* Wdt  = dir ? bWdt  : fWdt;
        const float* bdt  = dir ? bbdt  : fbdt;
        const float* Alog = dir ? bAlog : fAlog;
        const float* Dp   = dir ? bDp   : fDp;
        const float* WB   = dir ? bWB   : fWB;
        const float* WC   = dir ? bWC   : fWC;
        float* Xd = Xs[w];
        float* BCd = BCs[w];

        float xs[TSEQ];
        {
            F4 rw[16]; loadRow(rw, Wxz + lane * 64);
#pragma unroll
            for (int s = 0; s < TSEQ; s++) {
                int t = dir ? (TSEQ - 1 - s) : s;
                xs[s] = dot64(rw, Hs + t * 64);
            }
        }
        {
            float w0 = cw[lane * 4 + 0], w1 = cw[lane * 4 + 1];
            float w2 = cw[lane * 4 + 2], w3 = cw[lane * 4 + 3];
            float cb = cbp[lane];
#pragma unroll
            for (int s = 0; s < TSEQ; s++) {
                float a = cb + w3 * xs[s];
                if (s >= 1) a += w2 * xs[s - 1];
                if (s >= 2) a += w1 * xs[s - 2];
                if (s >= 3) a += w0 * xs[s - 3];
                float sig = 1.f / (1.f + __expf(-a));
                Xd[s * 68 + lane] = a * sig;
            }
        }
        __syncthreads();

        float dtv[TSEQ];
        {
            F4 rw[16]; loadRow(rw, Wdt + lane * 64);
            float bdv = bdt[lane];
#pragma unroll
            for (int s = 0; s < TSEQ; s++) {
                float a = bdv + dot64(rw, Xd + s * 68);
                dtv[s] = fmaxf(a, 0.f) + log1pf(__expf(-fabsf(a)));
            }
        }
        {
            // lane -> (s1 = lane>>3, n = lane&7); lanes<32 also cover s = 8 + (lane>>3)
            const int n = lane & 7, s1 = lane >> 3;
#pragma unroll 1
            for (int sel = 0; sel < 2; sel++) {
                F4 rw[16]; loadRow(rw, (sel ? WC : WB) + n * 64);
                BCd[s1 * 16 + sel * 8 + n] = dot64(rw, Xd + s1 * 68);
                if (lane < 32)
                    BCd[(8 + s1) * 16 + sel * 8 + n] = dot64(rw, Xd + (8 + s1) * 68);
            }
        }
        __syncthreads();

        {
            float An[8];
#pragma unroll
            for (int n2 = 0; n2 < 8; n2++) An[n2] = -__expf(Alog[lane * 8 + n2]);
            float dpv = Dp[lane];
            float st[8] = {0.f, 0.f, 0.f, 0.f, 0.f, 0.f, 0.f, 0.f};
#pragma unroll
            for (int s = 0; s < TSEQ; s++) {
                int t = dir ? (TSEQ - 1 - s) : s;
                float dtc = dtv[s];
                float xv = Hs[t * 64 + lane];
                float coef = xv * dtc;
                const float* bcp = BCd + s * 16;
                float y = 0.f;
#pragma unroll
                for (int n2 = 0; n2 < 8; n2++) {
                    float dA = __expf(An[n2] * dtc);
                    st[n2] = st[n2] * dA + coef * bcp[n2];
                    y += st[n2] * bcp[8 + n2];
                }
                Ys[t * 128 + (dir << 6) + lane] = y + xv * dpv;
            }
        }
        __syncthreads();
    }

    // ---- merge + residual + LN -> Ms : wave w handles t = 6w .. 6w+5
    {
        float mv[6];
        float bmv = bm[lane];
#pragma unroll
        for (int tt = 0; tt < 6; tt++) mv[tt] = bmv + Hs[(w * 6 + tt) * 64 + lane];
#pragma unroll 1
        for (int half = 0; half < 2; half++) {
            F4 rw[16]; loadRow(rw, Wm + lane * 128 + half * 64);
#pragma unroll
            for (int tt = 0; tt < 6; tt++)
                mv[tt] += dot64(rw, Ys + (w * 6 + tt) * 128 + half * 64);
        }
        float g = lng[lane], be = lnb[lane];
#pragma unroll
        for (int tt = 0; tt < 6; tt++) {
            float v = mv[tt];
            float s1 = v, s2 = v * v;
#pragma unroll
            for (int off = 1; off <= 32; off <<= 1) {
                s1 += __shfl_xor(s1, off);
                s2 += __shfl_xor(s2, off);
            }
            float mean = s1 * 0.015625f;
            float var = s2 * 0.015625f - mean * mean;
            float rs = rsqrtf(var + 1e-5f);
            Ms[(w * 6 + tt) * 64 + lane] = (v - mean) * rs * g + be;
        }
    }
    __syncthreads();

    // ---- out projection: wave w handles column chunks {2w, 2w+1}
#pragma unroll 1
    for (int ci2 = 0; ci2 < 2; ci2++) {
        int cidx = (w * 2 + ci2) * 64 + lane;
        bool act = cidx < COUT;
        F4 rw[16];
        float bov = 0.f;
        if (act) { loadRow(rw, Wo + (size_t)cidx * 64); bov = bo[cidx]; }
        for (int t = 0; t < TSEQ; t++) {
            if (act) {
                float a = bov + dot64(rw, Ms + t * 64);
                out[((size_t)b * TSEQ + t) * COUT + cidx] = a;
            }
        }
    }
}

// ---------------- host ---------------------------------------------------------------------
extern "C" void kernel_launch(void* const* d_in, const int* in_sizes, int n_in,
                              void* d_out, int out_size, void* d_ws, size_t ws_size,
                              hipStream_t stream) {
    (void)d_ws; (void)ws_size; (void)in_sizes; (void)n_in; (void)out_size;

    k_wsplit<<<(64 * KPAD) / 256, 256, 0, stream>>>((const float*)d_in[2]);

    k_gemm<<<MROWS / 32, 64, 0, stream>>>(
        (const float*)d_in[0], (const float*)d_in[1],
        (const float*)d_in[3], (const float*)d_in[4], (const float*)d_in[5]);

    k_ssm<<<BATCH, 128, 0, stream>>>(
        (const float*)d_in[6], (const float*)d_in[7], (const float*)d_in[8], (const float*)d_in[9],
        (const float*)d_in[10],
        (const float*)d_in[11], (const float*)d_in[12], (const float*)d_in[13], (const float*)d_in[14],
        (const float*)d_in[15], (const float*)d_in[16],
        (const int*)d_in[17], (const int*)d_in[18],
        (const float*)d_in[19], (const float*)d_in[20], (const float*)d_in[21], (const float*)d_in[22],
        (const float*)d_in[23], (const float*)d_in[24], (const float*)d_in[25], (const float*)d_in[26],
        (const float*)d_in[27],
        (const float*)d_in[28], (const float*)d_in[29], (const float*)d_in[30], (const float*)d_in[31],
        (const float*)d_in[32], (const float*)d_in[33], (const float*)d_in[34], (const float*)d_in[35],
        (const float*)d_in[36],
        (float*)d_out);
}

// Round 4
// 1505.892 us; speedup vs baseline: 1.7827x; 1.7827x over previous
//
#include <hip/hip_runtime.h>

typedef unsigned short u16;
typedef unsigned int u32;
typedef __attribute__((ext_vector_type(8))) short short8;
typedef __attribute__((ext_vector_type(4))) float fx4;

#define BATCH 4096
#define TSEQ 12
#define DIN 1536
#define DS 234
#define KTOT 1770
#define KPAD 1792
#define COUT 234
#define MROWS (BATCH * TSEQ)   // 49152

// phase fence: forbid the scheduler from hoisting the next phase's weight loads
// (64-VGPR arrays) above this point -- that hoisting is what blew register
// pressure to 256+ and generated GB-scale scratch spill traffic in R1-R3.
#define PHASE_FENCE() __builtin_amdgcn_sched_barrier(0)

union F4 { float4 v; float f[4]; u32 u[4]; };
union ABFrag { u32 u[4]; short8 s; uint4 q4; };

// persistent intermediates (module-static: no hipMalloc inside kernel_launch)
__device__ __attribute__((aligned(256))) u16 gWhi[64 * KPAD];
__device__ __attribute__((aligned(256))) u16 gWlo[64 * KPAD];
__device__ __attribute__((aligned(256))) float gH[(size_t)MROWS * 64];

// split x = hi + lo, hi = truncate-to-bf16 (top 16 bits), lo = bf16(x - hi).
// 3-term MFMA (ah*bh + al*bh + ah*bl) -> ~2^-15 relative product error.
__device__ __forceinline__ void splitPair(float x0, float x1, u32& hi, u32& lo) {
    union { float f; u32 u; } c0, c1, l0, l1;
    union { u32 u; float f; } g0, g1;
    c0.f = x0; c1.f = x1;
    u32 h0 = c0.u & 0xFFFF0000u;
    u32 h1 = c1.u & 0xFFFF0000u;
    g0.u = h0; g1.u = h1;
    l0.f = x0 - g0.f;
    l1.f = x1 - g1.f;
    hi = (h0 >> 16) | h1;
    lo = (l0.u >> 16) | (l1.u & 0xFFFF0000u);
}

__device__ __forceinline__ void splitFrag(const float a[8], ABFrag& ah, ABFrag& al) {
#pragma unroll
    for (int i = 0; i < 4; i++) splitPair(a[2 * i], a[2 * i + 1], ah.u[i], al.u[i]);
}

// 64-float weight row cached in 16 float4 VGPRs
__device__ __forceinline__ void loadRow(F4 (&w)[16], const float* base) {
#pragma unroll
    for (int i = 0; i < 16; i++) w[i].v = *(const float4*)(base + 4 * i);
}
__device__ __forceinline__ float dot64(const F4 (&w)[16], const float* v) {
    float a = 0.f, b = 0.f;
#pragma unroll
    for (int i = 0; i < 16; i++) {
        F4 h; h.v = *(const float4*)(v + 4 * i);   // LDS broadcast ds_read_b128
        a += w[i].f[0] * h.f[0] + w[i].f[1] * h.f[1];
        b += w[i].f[2] * h.f[2] + w[i].f[3] * h.f[3];
    }
    return a + b;
}

// ---------------- kernel 0: W_in -> bf16 hi/lo planes (K zero-padded to 1792) -------------
__global__ __launch_bounds__(256) void k_wsplit(const float* __restrict__ W_in) {
    int idx = blockIdx.x * 256 + threadIdx.x;        // 0 .. 64*1792-1
    int n = idx / KPAD, k = idx - n * KPAD;
    float w = (k < KTOT) ? W_in[n * KTOT + k] : 0.f;
    union { float f; u32 u; } c; c.f = w;
    u32 h = c.u & 0xFFFF0000u;
    union { u32 u; float f; } g; g.u = h;
    union { float f; u32 u; } l; l.f = w - g.f;
    gWhi[idx] = (u16)(h >> 16);
    gWlo[idx] = (u16)(l.u >> 16);
}

// ---------------- kernel 1: H = gelu(LN(X @ W^T + b)) ; X = [emb | fpass] ------------------
// one wave per block; each wave computes 16 M-rows x 64 cols, K = 1770.
// 3072 blocks = 12 waves/CU; plain launch_bounds (min-waves arg caused 84-VGPR spill builds).
__global__ __launch_bounds__(64) void k_gemm(
    const float* __restrict__ emb, const float* __restrict__ fpass,
    const float* __restrict__ b_in, const float* __restrict__ ln_in_g,
    const float* __restrict__ ln_in_b)
{
    const int lane = threadIdx.x;
    const int q = lane >> 4, cc = lane & 15;
    const int ko = q * 8;
    const int rowblk = blockIdx.x * 16;

    fx4 acc[4];
#pragma unroll
    for (int nt = 0; nt < 4; nt++) acc[nt] = (fx4){0.f, 0.f, 0.f, 0.f};

    const size_t m0 = (size_t)(rowblk + cc);
    const float* arow = emb + m0 * DIN + ko;
    const float* frow = fpass + m0 * DS + ko;
    const u16* whb = gWhi + cc * KPAD + ko;
    const u16* wlb = gWlo + cc * KPAD + ko;

    // emb part: K = 0..1535
    for (int kg = 0; kg < DIN; kg += 32) {
        ABFrag bh[4], bl[4];
#pragma unroll
        for (int nt = 0; nt < 4; nt++) {
            bh[nt].q4 = *(const uint4*)(whb + nt * 16 * KPAD + kg);
            bl[nt].q4 = *(const uint4*)(wlb + nt * 16 * KPAD + kg);
        }
        F4 a0, a1;
        a0.v = *(const float4*)(arow + kg);
        a1.v = *(const float4*)(arow + kg + 4);
        float av[8] = {a0.f[0], a0.f[1], a0.f[2], a0.f[3], a1.f[0], a1.f[1], a1.f[2], a1.f[3]};
        ABFrag ah, al;
        splitFrag(av, ah, al);
#pragma unroll
        for (int nt = 0; nt < 4; nt++) {
            acc[nt] = __builtin_amdgcn_mfma_f32_16x16x32_bf16(ah.s, bh[nt].s, acc[nt], 0, 0, 0);
            acc[nt] = __builtin_amdgcn_mfma_f32_16x16x32_bf16(al.s, bh[nt].s, acc[nt], 0, 0, 0);
            acc[nt] = __builtin_amdgcn_mfma_f32_16x16x32_bf16(ah.s, bl[nt].s, acc[nt], 0, 0, 0);
        }
    }
    // fpass part, full 32-wide steps: K = 1536..1759 (elem idx <= 223 < 234)
    for (int kg = 0; kg < 224; kg += 32) {
        ABFrag bh[4], bl[4];
#pragma unroll
        for (int nt = 0; nt < 4; nt++) {
            bh[nt].q4 = *(const uint4*)(whb + nt * 16 * KPAD + DIN + kg);
            bl[nt].q4 = *(const uint4*)(wlb + nt * 16 * KPAD + DIN + kg);
        }
        float2 a0 = *(const float2*)(frow + kg);
        float2 a1 = *(const float2*)(frow + kg + 2);
        float2 a2 = *(const float2*)(frow + kg + 4);
        float2 a3 = *(const float2*)(frow + kg + 6);
        float av[8] = {a0.x, a0.y, a1.x, a1.y, a2.x, a2.y, a3.x, a3.y};
        ABFrag ah, al;
        splitFrag(av, ah, al);
#pragma unroll
        for (int nt = 0; nt < 4; nt++) {
            acc[nt] = __builtin_amdgcn_mfma_f32_16x16x32_bf16(ah.s, bh[nt].s, acc[nt], 0, 0, 0);
            acc[nt] = __builtin_amdgcn_mfma_f32_16x16x32_bf16(al.s, bh[nt].s, acc[nt], 0, 0, 0);
            acc[nt] = __builtin_amdgcn_mfma_f32_16x16x32_bf16(ah.s, bl[nt].s, acc[nt], 0, 0, 0);
        }
    }
    // tail: elems 224..233 of fpass (W planes are zero-padded past 1770)
    {
        ABFrag bh[4], bl[4];
#pragma unroll
        for (int nt = 0; nt < 4; nt++) {
            bh[nt].q4 = *(const uint4*)(whb + nt * 16 * KPAD + DIN + 224);
            bl[nt].q4 = *(const uint4*)(wlb + nt * 16 * KPAD + DIN + 224);
        }
        float av[8];
#pragma unroll
        for (int j = 0; j < 8; j++) {
            int kk = 224 + ko + j;
            av[j] = (kk < DS) ? frow[224 + j] : 0.f;
        }
        ABFrag ah, al;
        splitFrag(av, ah, al);
#pragma unroll
        for (int nt = 0; nt < 4; nt++) {
            acc[nt] = __builtin_amdgcn_mfma_f32_16x16x32_bf16(ah.s, bh[nt].s, acc[nt], 0, 0, 0);
            acc[nt] = __builtin_amdgcn_mfma_f32_16x16x32_bf16(al.s, bh[nt].s, acc[nt], 0, 0, 0);
            acc[nt] = __builtin_amdgcn_mfma_f32_16x16x32_bf16(ah.s, bl[nt].s, acc[nt], 0, 0, 0);
        }
    }
    // epilogue: bias + LN(64) + GELU -> gH.  C/D: col = nt*16+cc, row = q*4+reg.
    float bia[4], gg[4], bb2[4];
#pragma unroll
    for (int nt = 0; nt < 4; nt++) {
        int col = nt * 16 + cc;
        bia[nt] = b_in[col]; gg[nt] = ln_in_g[col]; bb2[nt] = ln_in_b[col];
    }
#pragma unroll
    for (int rr = 0; rr < 4; rr++) {
        float vv[4], s1 = 0.f, s2 = 0.f;
#pragma unroll
        for (int nt = 0; nt < 4; nt++) {
            vv[nt] = acc[nt][rr] + bia[nt];
            s1 += vv[nt]; s2 += vv[nt] * vv[nt];
        }
#pragma unroll
        for (int off = 1; off <= 8; off <<= 1) {
            s1 += __shfl_xor(s1, off);
            s2 += __shfl_xor(s2, off);
        }
        float mean = s1 * 0.015625f;
        float var = s2 * 0.015625f - mean * mean;
        float rstd = rsqrtf(var + 1e-5f);
        size_t m = (size_t)(rowblk + q * 4 + rr);
#pragma unroll
        for (int nt = 0; nt < 4; nt++) {
            float x = (vv[nt] - mean) * rstd * gg[nt] + bb2[nt];
            float gel = 0.5f * x * (1.f + erff(x * 0.70710678118654752f));
            gH[m * 64 + nt * 16 + cc] = gel;
        }
    }
}

// ---------------- kernel 2: meta + pos + bidirectional SSM + merge + LN + out --------------
// 128 threads = 2 waves; wave w processes direction w (fwd/bwd independent until merge).
// PHASE_FENCE between phases pins each 64-VGPR weight array to its own phase (anti-spill).
__global__ __launch_bounds__(128) void k_ssm(
    const float* __restrict__ site_tab, const float* __restrict__ hour_tab,
    const float* __restrict__ W_meta, const float* __restrict__ b_meta,
    const float* __restrict__ pos_enc,
    const float* __restrict__ Wm, const float* __restrict__ bm,
    const float* __restrict__ lng, const float* __restrict__ lnb,
    const float* __restrict__ Wo, const float* __restrict__ bo,
    const int* __restrict__ site_ids, const int* __restrict__ hours,
    const float* __restrict__ fWxz, const float* __restrict__ fconvw, const float* __restrict__ fconvb,
    const float* __restrict__ fWdt, const float* __restrict__ fbdt, const float* __restrict__ fAlog,
    const float* __restrict__ fDp, const float* __restrict__ fWB, const float* __restrict__ fWC,
    const float* __restrict__ bWxz, const float* __restrict__ bconvw, const float* __restrict__ bconvb,
    const float* __restrict__ bWdt, const float* __restrict__ bbdt, const float* __restrict__ bAlog,
    const float* __restrict__ bDp, const float* __restrict__ bWB, const float* __restrict__ bWC,
    float* __restrict__ out)
{
    __shared__ __attribute__((aligned(16))) float Hs[TSEQ * 64];
    __shared__ __attribute__((aligned(16))) float Xs[2][TSEQ * 68];
    __shared__ __attribute__((aligned(16))) float BCs[2][TSEQ * 16];
    __shared__ __attribute__((aligned(16))) float Ys[TSEQ * 128];
    __shared__ __attribute__((aligned(16))) float Ms[TSEQ * 64];

    const int lane = threadIdx.x & 63;
    const int w = threadIdx.x >> 6;          // wave id == direction
    const int b = blockIdx.x;

    // meta for this lane's channel (computed redundantly by both waves)
    float metaV;
    {
        int sid = min(max(site_ids[b], 0), 19);
        int hr  = min(max(hours[b], 0), 23);
        float a = b_meta[lane];
#pragma unroll
        for (int j = 0; j < 8; j++) a += site_tab[sid * 8 + j] * W_meta[lane * 16 + j];
#pragma unroll
        for (int j = 0; j < 8; j++) a += hour_tab[hr * 8 + j] * W_meta[lane * 16 + 8 + j];
        metaV = a;
    }
    // H load + pos + meta: wave w writes t = 6w .. 6w+5
#pragma unroll
    for (int tt = 0; tt < 6; tt++) {
        int t = w * 6 + tt;
        Hs[t * 64 + lane] = gH[((size_t)b * TSEQ + t) * 64 + lane] + pos_enc[t * 64 + lane] + metaV;
    }
    PHASE_FENCE();
    __syncthreads();

    // ---- per-direction SSM (wave w handles dir w; lane = channel d)
    {
        const int dir = w;
        const float* Wxz  = dir ? bWxz  : fWxz;
        const float* cw   = dir ? bconvw : fconvw;
        const float* cbp  = dir ? bconvb : fconvb;
        const float* Wdt  = dir ? bWdt  : fWdt;
        const float* bdt  = dir ? bbdt  : fbdt;
        const float* Alog = dir ? bAlog : fAlog;
        const float* Dp   = dir ? bDp   : fDp;
        const float* WB   = dir ? bWB   : fWB;
        const float* WC   = dir ? bWC   : fWC;
        float* Xd = Xs[w];
        float* BCd = BCs[w];

        float xs[TSEQ];
        {
            F4 rw[16]; loadRow(rw, Wxz + lane * 64);
#pragma unroll
            for (int s = 0; s < TSEQ; s++) {
                int t = dir ? (TSEQ - 1 - s) : s;
                xs[s] = dot64(rw, Hs + t * 64);
            }
        }
        PHASE_FENCE();
        {
            float w0 = cw[lane * 4 + 0], w1 = cw[lane * 4 + 1];
            float w2 = cw[lane * 4 + 2], w3 = cw[lane * 4 + 3];
            float cb = cbp[lane];
#pragma unroll
            for (int s = 0; s < TSEQ; s++) {
                float a = cb + w3 * xs[s];
                if (s >= 1) a += w2 * xs[s - 1];
                if (s >= 2) a += w1 * xs[s - 2];
                if (s >= 3) a += w0 * xs[s - 3];
                float sig = 1.f / (1.f + __expf(-a));
                Xd[s * 68 + lane] = a * sig;
            }
        }
        PHASE_FENCE();
        __syncthreads();

        float dtv[TSEQ];
        {
            F4 rw[16]; loadRow(rw, Wdt + lane * 64);
            float bdv = bdt[lane];
#pragma unroll
            for (int s = 0; s < TSEQ; s++) {
                float a = bdv + dot64(rw, Xd + s * 68);
                dtv[s] = fmaxf(a, 0.f) + log1pf(__expf(-fabsf(a)));
            }
        }
        PHASE_FENCE();
        {
            // lane -> (s1 = lane>>3, n = lane&7); lanes<32 also cover s = 8 + (lane>>3)
            const int n = lane & 7, s1 = lane >> 3;
#pragma unroll 1
            for (int sel = 0; sel < 2; sel++) {
                F4 rw[16]; loadRow(rw, (sel ? WC : WB) + n * 64);
                BCd[s1 * 16 + sel * 8 + n] = dot64(rw, Xd + s1 * 68);
                if (lane < 32)
                    BCd[(8 + s1) * 16 + sel * 8 + n] = dot64(rw, Xd + (8 + s1) * 68);
                PHASE_FENCE();
            }
        }
        __syncthreads();

        {
            float An[8];
#pragma unroll
            for (int n2 = 0; n2 < 8; n2++) An[n2] = -__expf(Alog[lane * 8 + n2]);
            float dpv = Dp[lane];
            float st[8] = {0.f, 0.f, 0.f, 0.f, 0.f, 0.f, 0.f, 0.f};
#pragma unroll
            for (int s = 0; s < TSEQ; s++) {
                int t = dir ? (TSEQ - 1 - s) : s;
                float dtc = dtv[s];
                float xv = Hs[t * 64 + lane];
                float coef = xv * dtc;
                const float* bcp = BCd + s * 16;
                float y = 0.f;
#pragma unroll
                for (int n2 = 0; n2 < 8; n2++) {
                    float dA = __expf(An[n2] * dtc);
                    st[n2] = st[n2] * dA + coef * bcp[n2];
                    y += st[n2] * bcp[8 + n2];
                }
                Ys[t * 128 + (dir << 6) + lane] = y + xv * dpv;
            }
        }
        PHASE_FENCE();
        __syncthreads();
    }

    // ---- merge + residual + LN -> Ms : wave w handles t = 6w .. 6w+5
    {
        float mv[6];
        float bmv = bm[lane];
#pragma unroll
        for (int tt = 0; tt < 6; tt++) mv[tt] = bmv + Hs[(w * 6 + tt) * 64 + lane];
#pragma unroll 1
        for (int half = 0; half < 2; half++) {
            F4 rw[16]; loadRow(rw, Wm + lane * 128 + half * 64);
#pragma unroll
            for (int tt = 0; tt < 6; tt++)
                mv[tt] += dot64(rw, Ys + (w * 6 + tt) * 128 + half * 64);
            PHASE_FENCE();
        }
        float g = lng[lane], be = lnb[lane];
#pragma unroll
        for (int tt = 0; tt < 6; tt++) {
            float v = mv[tt];
            float s1 = v, s2 = v * v;
#pragma unroll
            for (int off = 1; off <= 32; off <<= 1) {
                s1 += __shfl_xor(s1, off);
                s2 += __shfl_xor(s2, off);
            }
            float mean = s1 * 0.015625f;
            float var = s2 * 0.015625f - mean * mean;
            float rs = rsqrtf(var + 1e-5f);
            Ms[(w * 6 + tt) * 64 + lane] = (v - mean) * rs * g + be;
        }
    }
    PHASE_FENCE();
    __syncthreads();

    // ---- out projection: wave w handles column chunks {2w, 2w+1}
#pragma unroll 1
    for (int ci2 = 0; ci2 < 2; ci2++) {
        int cidx = (w * 2 + ci2) * 64 + lane;
        bool act = cidx < COUT;
        F4 rw[16];
        float bov = 0.f;
        if (act) { loadRow(rw, Wo + (size_t)cidx * 64); bov = bo[cidx]; }
        for (int t = 0; t < TSEQ; t++) {
            if (act) {
                float a = bov + dot64(rw, Ms + t * 64);
                out[((size_t)b * TSEQ + t) * COUT + cidx] = a;
            }
        }
        PHASE_FENCE();
    }
}

// ---------------- host ---------------------------------------------------------------------
extern "C" void kernel_launch(void* const* d_in, const int* in_sizes, int n_in,
                              void* d_out, int out_size, void* d_ws, size_t ws_size,
                              hipStream_t stream) {
    (void)d_ws; (void)ws_size; (void)in_sizes; (void)n_in; (void)out_size;

    k_wsplit<<<(64 * KPAD) / 256, 256, 0, stream>>>((const float*)d_in[2]);

    k_gemm<<<MROWS / 16, 64, 0, stream>>>(
        (const float*)d_in[0], (const float*)d_in[1],
        (const float*)d_in[3], (const float*)d_in[4], (const float*)d_in[5]);

    k_ssm<<<BATCH, 128, 0, stream>>>(
        (const float*)d_in[6], (const float*)d_in[7], (const float*)d_in[8], (const float*)d_in[9],
        (const float*)d_in[10],
        (const float*)d_in[11], (const float*)d_in[12], (const float*)d_in[13], (const float*)d_in[14],
        (const float*)d_in[15], (const float*)d_in[16],
        (const int*)d_in[17], (const int*)d_in[18],
        (const float*)d_in[19], (const float*)d_in[20], (const float*)d_in[21], (const float*)d_in[22],
        (const float*)d_in[23], (const float*)d_in[24], (const float*)d_in[25], (const float*)d_in[26],
        (const float*)d_in[27],
        (const float*)d_in[28], (const float*)d_in[29], (const float*)d_in[30], (const float*)d_in[31],
        (const float*)d_in[32], (const float*)d_in[33], (const float*)d_in[34], (const float*)d_in[35],
        (const float*)d_in[36],
        (float*)d_out);
}